// Round 15
// baseline (366.309 us; speedup 1.0000x reference)
//
#include <hip/hip_runtime.h>
#include <hip/hip_bf16.h>

#define Bb 4
#define Cc 96
#define Hh 256
#define Ww 512
#define OC 192
#define HO 128
#define WO 256
#define Gg 16
#define CPG 6

typedef __attribute__((ext_vector_type(4))) float f32x4;
typedef __attribute__((ext_vector_type(8))) short bf16x8;
typedef __attribute__((ext_vector_type(4))) short bf16x4;

static __device__ __forceinline__ ushort f2b(float f) {
    __hip_bfloat16 h = __float2bfloat16(f);
    return *reinterpret_cast<ushort*>(&h);
}
static __device__ __forceinline__ float b2f(ushort u) {
    unsigned int v = ((unsigned int)u) << 16;
    return __builtin_bit_cast(float, v);
}

// ---------------------------------------------------------------------------
// Pack w1, MFMA fragment order, klocal = q*8 + j (verified R7).
// ---------------------------------------------------------------------------
__global__ __launch_bounds__(64) void pack_w1(const float* __restrict__ w1,
                                              ushort* __restrict__ apack) {
    const int blk = blockIdx.x;      // 27*12
    const int k0 = blk / 12;
    const int mf = blk % 12;
    const int lane = threadIdx.x;
    const int m = mf * 16 + (lane & 15);
    const int chunk = k0 / 9;
    const int tap = k0 % 9;
    ushort* dst = apack + (((size_t)(k0 * 12 + mf) * 64) + lane) * 8;
#pragma unroll
    for (int j = 0; j < 8; ++j) {
        const int klocal = ((lane >> 4) << 3) + j;
        const int ic = chunk * 32 + klocal;
        dst[j] = f2b(w1[(size_t)(m * Cc + ic) * 9 + tap]);
    }
}

// ---------------------------------------------------------------------------
// Pack w2, softmax-group row permutation (verified R5) + klocal = q*8+j (R7).
// ---------------------------------------------------------------------------
__global__ __launch_bounds__(64) void pack_w2(const float* __restrict__ w2,
                                              ushort* __restrict__ w2p) {
    const int blk = blockIdx.x;      // 6*9
    const int ks = blk / 9;
    const int mf = blk % 9;
    const int lane = threadIdx.x;
    const int X = lane & 15;
    const int qq = X >> 2;
    const int rr = X & 3;
    const int s = mf * 4 + rr;
    const int g = qq * 4 + s / 9;
    const int k = s % 9;
    const int m = g * 9 + k;
    ushort* dst = w2p + (((size_t)(ks * 9 + mf) * 64) + lane) * 8;
#pragma unroll
    for (int j = 0; j < 8; ++j) {
        const int klocal = ((lane >> 4) << 3) + j;
        const int c = ks * 32 + klocal;
        dst[j] = f2b(w2[(size_t)m * OC + c]);
    }
}

// ---------------------------------------------------------------------------
// Fused kernel — R14 structure + T14 async-STAGE split: next chunk's global
// loads are issued into registers BEFORE the current chunk's MFMA phase, so
// HBM latency hides under compute. pre0/1/2 are static-indexed (rule #20).
// __launch_bounds__(512,4): VGPR cap 128 >= ~120 need -> no spill, 2 blk/CU.
// LDS (octet-major): xl [6][4][128][8]=49152 B (+halo) | yl | p  (union).
// Grid 1024, bijective XCD swizzle.
// ---------------------------------------------------------------------------
#define XL_MAIN (6 * 4 * 128 * 8)         // 24576 ushorts
#define UNION_USHORTS (XL_MAIN + 3 * 32)  // 24672 ushorts = 49344 B

#define ISSUE_LOADS(CH)                                                        \
    {                                                                          \
        const int icc_ = (CH) * 32;                                            \
        _Pragma("unroll")                                                      \
        for (int it = 0; it < 3; ++it) {                                       \
            const int g2 = tid + (it << 9);                                    \
            const int oct = g2 & 3;                                            \
            const int colp = (g2 >> 2) & 127;                                  \
            const int row = g2 >> 9;                                           \
            const int ih = 2 * oh - 1 + row;                                   \
            const int gcol = 2 * ow0 + 2 * colp;                               \
            float2* dst = (it == 0) ? pre0 : (it == 1) ? pre1 : pre2;          \
            if (ih >= 0) {                                                     \
                const float* xp = x + ((size_t)(b * Cc + icc_ + (oct << 3)) * Hh + ih) * Ww + gcol; \
                _Pragma("unroll")                                              \
                for (int j = 0; j < 8; ++j)                                    \
                    dst[j] = *reinterpret_cast<const float2*>(xp + (size_t)j * chs); \
            } else {                                                           \
                _Pragma("unroll")                                              \
                for (int j = 0; j < 8; ++j) dst[j] = make_float2(0.f, 0.f);    \
            }                                                                  \
        }                                                                      \
        if (tid < 12) {                                                        \
            const int oct = tid & 3;                                           \
            const int row = tid >> 2;                                          \
            const int ih = 2 * oh - 1 + row;                                   \
            const int gcol = 2 * ow0 - 1;                                      \
            if (ih >= 0 && gcol >= 0) {                                        \
                const float* xp = x + ((size_t)(b * Cc + icc_ + (oct << 3)) * Hh + ih) * Ww + gcol; \
                _Pragma("unroll")                                              \
                for (int j = 0; j < 8; ++j) preh[j] = xp[(size_t)j * chs];     \
            } else {                                                           \
                _Pragma("unroll")                                              \
                for (int j = 0; j < 8; ++j) preh[j] = 0.f;                     \
            }                                                                  \
        }                                                                      \
    }

__global__ __launch_bounds__(512, 4) void fused(
        const float* __restrict__ x, const ushort* __restrict__ apack,
        const ushort* __restrict__ w2p,
        const float* __restrict__ gamma, const float* __restrict__ beta,
        float* __restrict__ out) {
    __shared__ __align__(16) ushort smem[UNION_USHORTS];
    __shared__ float sc[OC], bi[OC];

    // bijective XCD swizzle (1024 % 8 == 0): 128 contiguous blocks per XCD
    const int bid0 = blockIdx.x;
    const int bid = (bid0 & 7) * 128 + (bid0 >> 3);
    const int owt = bid & 1;
    const int oh = (bid >> 1) & 127;
    const int b = bid >> 8;
    const int ow0 = owt * 128;
    const int tid = threadIdx.x;
    const int wid = tid >> 6;       // 0..7
    const int wm = wid & 1;         // conv M half: oc base wm*96
    const int wn = wid >> 1;        // conv N quarter: ow base wn*32
    const int lane = tid & 63;
    const int r = lane & 15;
    const int q = lane >> 4;

    if (tid < OC) {
        const float bnr = 1.0f / sqrtf(1.0f + 1e-5f);
        sc[tid] = gamma[tid] * bnr;
        bi[tid] = beta[tid];
    }

    f32x4 cacc[6][2];
#pragma unroll
    for (int mf = 0; mf < 6; ++mf)
#pragma unroll
        for (int nf = 0; nf < 2; ++nf) cacc[mf][nf] = (f32x4){0.f, 0.f, 0.f, 0.f};

    const size_t chs = (size_t)Hh * Ww;

    // prefetch registers (persistent across chunk loop; all static-indexed)
    float2 pre0[8], pre1[8], pre2[8];
    float preh[8];

    // ================= conv phase (async-STAGE pipelined) =================
    ISSUE_LOADS(0);
    for (int chunk = 0; chunk < 3; ++chunk) {
        __syncthreads();   // previous chunk's xl readers done
        // ---- write prefetched regs -> xl (vmcnt wait folds in here) ----
#pragma unroll
        for (int it = 0; it < 3; ++it) {
            const int g2 = tid + (it << 9);
            const int oct = g2 & 3;
            const int colp = (g2 >> 2) & 127;
            const int row = g2 >> 9;
            const float2* src = (it == 0) ? pre0 : (it == 1) ? pre1 : pre2;
            bf16x8 u0, u1;
#pragma unroll
            for (int j = 0; j < 8; ++j) {
                u0[j] = (short)f2b(src[j].x);
                u1[j] = (short)f2b(src[j].y);
            }
            *reinterpret_cast<bf16x8*>(smem + (((row * 2 + 0) * 4 + oct) * 128 + colp) * 8) = u0;
            *reinterpret_cast<bf16x8*>(smem + (((row * 2 + 1) * 4 + oct) * 128 + colp) * 8) = u1;
        }
        if (tid < 12) {
            const int oct = tid & 3;
            const int row = tid >> 2;
            bf16x8 u;
#pragma unroll
            for (int j = 0; j < 8; ++j) u[j] = (short)f2b(preh[j]);
            *reinterpret_cast<bf16x8*>(smem + XL_MAIN + row * 32 + oct * 8) = u;
        }
        __syncthreads();   // xl ready
        // ---- issue NEXT chunk's loads (latency hides under MFMA below) ----
        if (chunk == 0)      ISSUE_LOADS(1)
        else if (chunk == 1) ISSUE_LOADS(2)

        // ---- compute 9 taps ----
#pragma unroll
        for (int tap = 0; tap < 9; ++tap) {
            const int kh = tap / 3, kw = tap % 3;
            const int par = (kw == 1) ? 0 : 1;
            const int cb = (kw == 0) ? -1 : 0;
            const int k0 = chunk * 9 + tap;

            bf16x8 af[6];
            const ushort* ap = apack + (((size_t)(k0 * 12 + wm * 6) * 64) + lane) * 8;
#pragma unroll
            for (int mf = 0; mf < 6; ++mf)
                af[mf] = *reinterpret_cast<const bf16x8*>(ap + (size_t)mf * 64 * 8);

            bf16x8 bfr[2];
#pragma unroll
            for (int nf = 0; nf < 2; ++nf) {
                const int n = wn * 32 + nf * 16 + r;
                const int colc = n + cb;
                const ushort* src = (colc >= 0)
                    ? smem + (((kh * 2 + par) * 4 + q) * 128 + colc) * 8
                    : smem + XL_MAIN + kh * 32 + q * 8;
                bfr[nf] = *reinterpret_cast<const bf16x8*>(src);
            }
#pragma unroll
            for (int mf = 0; mf < 6; ++mf)
#pragma unroll
                for (int nf = 0; nf < 2; ++nf)
                    cacc[mf][nf] = __builtin_amdgcn_mfma_f32_16x16x32_bf16(
                        af[mf], bfr[nf], cacc[mf][nf], 0, 0, 0);
        }
    }

    // ====== epilogue: BN+LReLU -> yl[coct][ow][8] bf16 ======
    __syncthreads();
#pragma unroll
    for (int mf = 0; mf < 6; ++mf) {
        const int cbase = wm * 96 + mf * 16;
        const int coct = (cbase >> 3) + (q >> 1);
#pragma unroll
        for (int nf = 0; nf < 2; ++nf) {
            const int ow = wn * 32 + nf * 16 + r;
            ushort pk[4];
#pragma unroll
            for (int rr = 0; rr < 4; ++rr) {
                const int oc = cbase + q * 4 + rr;
                float v = cacc[mf][nf][rr] * sc[oc] + bi[oc];
                v = (v >= 0.f) ? v : 0.1f * v;
                pk[rr] = f2b(v);
            }
            *reinterpret_cast<bf16x4*>(smem + (coct * 128 + ow) * 8 + (q & 1) * 4) =
                *reinterpret_cast<bf16x4*>(pk);
        }
    }
    __syncthreads();

    // ============ logits MFMA: wave-half mf split, shared af loads ============
    const int hi = wid >> 2;         // 0: mf 0..4, 1: mf 4..8
    const int mfbase = hi * 4;
    f32x4 macc[5], macc2[5];
#pragma unroll
    for (int mf = 0; mf < 5; ++mf) {
        macc[mf] = (f32x4){0.f, 0.f, 0.f, 0.f};
        macc2[mf] = (f32x4){0.f, 0.f, 0.f, 0.f};
    }
#pragma unroll
    for (int ks = 0; ks < 6; ++ks) {
        bf16x8 af[5];
        const ushort* ap = w2p + (((size_t)(ks * 9 + mfbase) * 64) + lane) * 8;
#pragma unroll
        for (int mf = 0; mf < 5; ++mf)
            af[mf] = *reinterpret_cast<const bf16x8*>(ap + (size_t)mf * 64 * 8);
        const bf16x8 bfr0 = *reinterpret_cast<const bf16x8*>(
            smem + ((ks * 4 + q) * 128 + (wid & 3) * 32 + r) * 8);
        const bf16x8 bfr1 = *reinterpret_cast<const bf16x8*>(
            smem + ((ks * 4 + q) * 128 + (wid & 3) * 32 + 16 + r) * 8);
#pragma unroll
        for (int mf = 0; mf < 5; ++mf) {
            macc[mf] = __builtin_amdgcn_mfma_f32_16x16x32_bf16(af[mf], bfr0, macc[mf], 0, 0, 0);
            macc2[mf] = __builtin_amdgcn_mfma_f32_16x16x32_bf16(af[mf], bfr1, macc2[mf], 0, 0, 0);
        }
    }
    __syncthreads();   // yl reads done; p overwrites

    // ===== branch-static softmax -> p[144][128] (rule #20: hi wave-uniform) =====
    if (hi == 0) {
#pragma unroll
        for (int nf = 0; nf < 2; ++nf) {
            const int ow = (wid & 3) * 32 + nf * 16 + r;
            const int col = (ow + q * 16) & 127;
            const f32x4(&mc)[5] = (nf == 0) ? macc : macc2;
#pragma unroll
            for (int gi = 0; gi < 2; ++gi) {
                const int gl = gi;                       // 0,1
                const int g = q * 4 + gl;
                float pv[9]; float mx = -1e30f;
#pragma unroll
                for (int k = 0; k < 9; ++k) {
                    const int s = gl * 9 + k;
                    pv[k] = mc[s >> 2][s & 3];
                    mx = fmaxf(mx, pv[k]);
                }
                float ssum = 0.f;
#pragma unroll
                for (int k = 0; k < 9; ++k) { pv[k] = __expf(pv[k] - mx); ssum += pv[k]; }
                const float inv = 1.f / ssum;
#pragma unroll
                for (int k = 0; k < 9; ++k)
                    smem[(g * 9 + k) * 128 + col] = f2b(pv[k] * inv);
            }
        }
    } else {
#pragma unroll
        for (int nf = 0; nf < 2; ++nf) {
            const int ow = (wid & 3) * 32 + nf * 16 + r;
            const int col = (ow + q * 16) & 127;
            const f32x4(&mc)[5] = (nf == 0) ? macc : macc2;
#pragma unroll
            for (int gi = 0; gi < 2; ++gi) {
                const int gl = 2 + gi;                   // 2,3
                const int g = q * 4 + gl;
                float pv[9]; float mx = -1e30f;
#pragma unroll
                for (int k = 0; k < 9; ++k) {
                    const int s = gl * 9 + k;
                    pv[k] = mc[(s >> 2) - 4][s & 3];
                    mx = fmaxf(mx, pv[k]);
                }
                float ssum = 0.f;
#pragma unroll
                for (int k = 0; k < 9; ++k) { pv[k] = __expf(pv[k] - mx); ssum += pv[k]; }
                const float inv = 1.f / ssum;
#pragma unroll
                for (int k = 0; k < 9; ++k)
                    smem[(g * 9 + k) * 128 + col] = f2b(pv[k] * inv);
            }
        }
    }
    __syncthreads();

    // ============ apply phase (coalesced) ============
    const int ih0 = 2 * oh - 1;
    const bool okh0 = (oh > 0);
#pragma unroll
    for (int it = 0; it < 4; ++it) {
        const int idx = (it << 9) + tid;
        const int g = idx >> 7;                 // 0..15, wave-uniform
        const int owl = idx & 127;
        const int owg = ow0 + owl;
        const int col = (owl + (g >> 2) * 16) & 127;

        float p[9];
#pragma unroll
        for (int k = 0; k < 9; ++k) p[k] = b2f(smem[(g * 9 + k) * 128 + col]);

        const int iw0 = 2 * owg - 1;
        const bool okw0 = (owg > 0);
#pragma unroll
        for (int i = 0; i < CPG; ++i) {
            const int cc = i * Gg + g;
            const float* xc = x + (size_t)(b * Cc + cc) * chs;
            float acc = 0.f;
#pragma unroll
            for (int kh = 0; kh < 3; ++kh) {
                if (kh == 0 && !okh0) continue;
                const float* rowp = xc + (size_t)(ih0 + kh) * Ww + iw0;
                const float v0 = okw0 ? rowp[0] : 0.f;
                const float2 v12 = *reinterpret_cast<const float2*>(rowp + 1);
                acc += p[kh * 3 + 0] * v0 + p[kh * 3 + 1] * v12.x
                     + p[kh * 3 + 2] * v12.y;
            }
            out[((size_t)(b * Cc + cc) * HO + oh) * WO + owg] = acc;
        }
    }
}

extern "C" void kernel_launch(void* const* d_in, const int* in_sizes, int n_in,
                              void* d_out, int out_size, void* d_ws, size_t ws_size,
                              hipStream_t stream) {
    const float* x     = (const float*)d_in[0];
    const float* w1    = (const float*)d_in[1];
    const float* gamma = (const float*)d_in[2];
    const float* beta  = (const float*)d_in[3];
    const float* w2    = (const float*)d_in[4];
    float* out = (float*)d_out;

    ushort* apack = (ushort*)d_ws;                           // 331,776 B
    ushort* w2p   = (ushort*)((char*)d_ws + 331776);         // + 55,296 B

    pack_w1<<<27 * 12, 64, 0, stream>>>(w1, apack);
    pack_w2<<<6 * 9, 64, 0, stream>>>(w2, w2p);
    fused<<<Bb * HO * 2, 512, 0, stream>>>(x, apack, w2p, gamma, beta, out);
}

// Round 16
// 225.806 us; speedup vs baseline: 1.6222x; 1.6222x over previous
//
#include <hip/hip_runtime.h>
#include <hip/hip_bf16.h>

#define Bb 4
#define Cc 96
#define Hh 256
#define Ww 512
#define OC 192
#define HO 128
#define WO 256
#define Gg 16
#define CPG 6

typedef __attribute__((ext_vector_type(4))) float f32x4;
typedef __attribute__((ext_vector_type(8))) short bf16x8;
typedef __attribute__((ext_vector_type(4))) short bf16x4;

static __device__ __forceinline__ ushort f2b(float f) {
    __hip_bfloat16 h = __float2bfloat16(f);
    return *reinterpret_cast<ushort*>(&h);
}
static __device__ __forceinline__ float b2f(ushort u) {
    unsigned int v = ((unsigned int)u) << 16;
    return __builtin_bit_cast(float, v);
}

// ---------------------------------------------------------------------------
// Pack w1, MFMA fragment order, klocal = q*8 + j (verified R7).
// ---------------------------------------------------------------------------
__global__ __launch_bounds__(64) void pack_w1(const float* __restrict__ w1,
                                              ushort* __restrict__ apack) {
    const int blk = blockIdx.x;      // 27*12
    const int k0 = blk / 12;
    const int mf = blk % 12;
    const int lane = threadIdx.x;
    const int m = mf * 16 + (lane & 15);
    const int chunk = k0 / 9;
    const int tap = k0 % 9;
    ushort* dst = apack + (((size_t)(k0 * 12 + mf) * 64) + lane) * 8;
#pragma unroll
    for (int j = 0; j < 8; ++j) {
        const int klocal = ((lane >> 4) << 3) + j;
        const int ic = chunk * 32 + klocal;
        dst[j] = f2b(w1[(size_t)(m * Cc + ic) * 9 + tap]);
    }
}

// ---------------------------------------------------------------------------
// Pack w2, softmax-group row permutation (verified R5) + klocal = q*8+j (R7).
// ---------------------------------------------------------------------------
__global__ __launch_bounds__(64) void pack_w2(const float* __restrict__ w2,
                                              ushort* __restrict__ w2p) {
    const int blk = blockIdx.x;      // 6*9
    const int ks = blk / 9;
    const int mf = blk % 9;
    const int lane = threadIdx.x;
    const int X = lane & 15;
    const int qq = X >> 2;
    const int rr = X & 3;
    const int s = mf * 4 + rr;
    const int g = qq * 4 + s / 9;
    const int k = s % 9;
    const int m = g * 9 + k;
    ushort* dst = w2p + (((size_t)(ks * 9 + mf) * 64) + lane) * 8;
#pragma unroll
    for (int j = 0; j < 8; ++j) {
        const int klocal = ((lane >> 4) << 3) + j;
        const int c = ks * 32 + klocal;
        dst[j] = f2b(w2[(size_t)m * OC + c]);
    }
}

// ---------------------------------------------------------------------------
// T14 helpers: NAMED static arrays only (rule #20: no runtime pointer select).
// ---------------------------------------------------------------------------
template<int IT>
static __device__ __forceinline__ void issue_loads_it(
        float2 (&dst)[8], const float* __restrict__ x,
        int tid, int oh, int ow0, int b, int icc, size_t chs) {
    const int g2 = tid + (IT << 9);
    const int oct = g2 & 3;
    const int colp = (g2 >> 2) & 127;
    const int row = g2 >> 9;
    const int ih = 2 * oh - 1 + row;
    const int gcol = 2 * ow0 + 2 * colp;
    if (ih >= 0) {
        const float* xp = x + ((size_t)(b * Cc + icc + (oct << 3)) * Hh + ih) * Ww + gcol;
#pragma unroll
        for (int j = 0; j < 8; ++j)
            dst[j] = *reinterpret_cast<const float2*>(xp + (size_t)j * chs);
    } else {
#pragma unroll
        for (int j = 0; j < 8; ++j) dst[j] = make_float2(0.f, 0.f);
    }
}

template<int IT>
static __device__ __forceinline__ void write_stage_it(
        const float2 (&src)[8], ushort* __restrict__ smem, int tid) {
    const int g2 = tid + (IT << 9);
    const int oct = g2 & 3;
    const int colp = (g2 >> 2) & 127;
    const int row = g2 >> 9;
    bf16x8 u0, u1;
#pragma unroll
    for (int j = 0; j < 8; ++j) {
        u0[j] = (short)f2b(src[j].x);
        u1[j] = (short)f2b(src[j].y);
    }
    *reinterpret_cast<bf16x8*>(smem + (((row * 2 + 0) * 4 + oct) * 128 + colp) * 8) = u0;
    *reinterpret_cast<bf16x8*>(smem + (((row * 2 + 1) * 4 + oct) * 128 + colp) * 8) = u1;
}

// ---------------------------------------------------------------------------
// Fused kernel — R14 structure + T14 async-STAGE (static regs).
// No launch-bounds 2nd arg: allocator free (~150 VGPR) -> 2 blocks/CU,
// grid 1024 = exactly 2 rounds. LDS union 49344 B as R14.
// ---------------------------------------------------------------------------
#define XL_MAIN (6 * 4 * 128 * 8)         // 24576 ushorts
#define UNION_USHORTS (XL_MAIN + 3 * 32)  // 24672 ushorts = 49344 B

__global__ __launch_bounds__(512) void fused(
        const float* __restrict__ x, const ushort* __restrict__ apack,
        const ushort* __restrict__ w2p,
        const float* __restrict__ gamma, const float* __restrict__ beta,
        float* __restrict__ out) {
    __shared__ __align__(16) ushort smem[UNION_USHORTS];
    __shared__ float sc[OC], bi[OC];

    // bijective XCD swizzle (1024 % 8 == 0): 128 contiguous blocks per XCD
    const int bid0 = blockIdx.x;
    const int bid = (bid0 & 7) * 128 + (bid0 >> 3);
    const int owt = bid & 1;
    const int oh = (bid >> 1) & 127;
    const int b = bid >> 8;
    const int ow0 = owt * 128;
    const int tid = threadIdx.x;
    const int wid = tid >> 6;       // 0..7
    const int wm = wid & 1;         // conv M half: oc base wm*96
    const int wn = wid >> 1;        // conv N quarter: ow base wn*32
    const int lane = tid & 63;
    const int r = lane & 15;
    const int q = lane >> 4;

    if (tid < OC) {
        const float bnr = 1.0f / sqrtf(1.0f + 1e-5f);
        sc[tid] = gamma[tid] * bnr;
        bi[tid] = beta[tid];
    }

    f32x4 cacc[6][2];
#pragma unroll
    for (int mf = 0; mf < 6; ++mf)
#pragma unroll
        for (int nf = 0; nf < 2; ++nf) cacc[mf][nf] = (f32x4){0.f, 0.f, 0.f, 0.f};

    const size_t chs = (size_t)Hh * Ww;

    // prefetch registers — named, statically indexed everywhere
    float2 pre0[8], pre1[8], pre2[8];
    float preh[8];

    // issue chunk-0 loads
    issue_loads_it<0>(pre0, x, tid, oh, ow0, b, 0, chs);
    issue_loads_it<1>(pre1, x, tid, oh, ow0, b, 0, chs);
    issue_loads_it<2>(pre2, x, tid, oh, ow0, b, 0, chs);
    if (tid < 12) {
        const int oct = tid & 3;
        const int row = tid >> 2;
        const int ih = 2 * oh - 1 + row;
        const int gcol = 2 * ow0 - 1;
        if (ih >= 0 && gcol >= 0) {
            const float* xp = x + ((size_t)(b * Cc + (oct << 3)) * Hh + ih) * Ww + gcol;
#pragma unroll
            for (int j = 0; j < 8; ++j) preh[j] = xp[(size_t)j * chs];
        } else {
#pragma unroll
            for (int j = 0; j < 8; ++j) preh[j] = 0.f;
        }
    }

    // ================= conv phase (async-STAGE pipelined) =================
    for (int chunk = 0; chunk < 3; ++chunk) {
        __syncthreads();   // previous chunk's xl readers done
        // ---- write prefetched regs -> xl ----
        write_stage_it<0>(pre0, smem, tid);
        write_stage_it<1>(pre1, smem, tid);
        write_stage_it<2>(pre2, smem, tid);
        if (tid < 12) {
            const int oct = tid & 3;
            const int row = tid >> 2;
            bf16x8 u;
#pragma unroll
            for (int j = 0; j < 8; ++j) u[j] = (short)f2b(preh[j]);
            *reinterpret_cast<bf16x8*>(smem + XL_MAIN + row * 32 + oct * 8) = u;
        }
        __syncthreads();   // xl ready

        // ---- issue NEXT chunk's loads (latency hides under MFMA below) ----
        if (chunk < 2) {
            const int icc = (chunk + 1) * 32;
            issue_loads_it<0>(pre0, x, tid, oh, ow0, b, icc, chs);
            issue_loads_it<1>(pre1, x, tid, oh, ow0, b, icc, chs);
            issue_loads_it<2>(pre2, x, tid, oh, ow0, b, icc, chs);
            if (tid < 12) {
                const int oct = tid & 3;
                const int row = tid >> 2;
                const int ih = 2 * oh - 1 + row;
                const int gcol = 2 * ow0 - 1;
                if (ih >= 0 && gcol >= 0) {
                    const float* xp = x + ((size_t)(b * Cc + icc + (oct << 3)) * Hh + ih) * Ww + gcol;
#pragma unroll
                    for (int j = 0; j < 8; ++j) preh[j] = xp[(size_t)j * chs];
                } else {
#pragma unroll
                    for (int j = 0; j < 8; ++j) preh[j] = 0.f;
                }
            }
        }

        // ---- compute 9 taps ----
#pragma unroll
        for (int tap = 0; tap < 9; ++tap) {
            const int kh = tap / 3, kw = tap % 3;
            const int par = (kw == 1) ? 0 : 1;
            const int cb = (kw == 0) ? -1 : 0;
            const int k0 = chunk * 9 + tap;

            bf16x8 af[6];
            const ushort* ap = apack + (((size_t)(k0 * 12 + wm * 6) * 64) + lane) * 8;
#pragma unroll
            for (int mf = 0; mf < 6; ++mf)
                af[mf] = *reinterpret_cast<const bf16x8*>(ap + (size_t)mf * 64 * 8);

            bf16x8 bfr[2];
#pragma unroll
            for (int nf = 0; nf < 2; ++nf) {
                const int n = wn * 32 + nf * 16 + r;
                const int colc = n + cb;
                const ushort* src = (colc >= 0)
                    ? smem + (((kh * 2 + par) * 4 + q) * 128 + colc) * 8
                    : smem + XL_MAIN + kh * 32 + q * 8;
                bfr[nf] = *reinterpret_cast<const bf16x8*>(src);
            }
#pragma unroll
            for (int mf = 0; mf < 6; ++mf)
#pragma unroll
                for (int nf = 0; nf < 2; ++nf)
                    cacc[mf][nf] = __builtin_amdgcn_mfma_f32_16x16x32_bf16(
                        af[mf], bfr[nf], cacc[mf][nf], 0, 0, 0);
        }
    }

    // ====== epilogue: BN+LReLU -> yl[coct][ow][8] bf16 ======
    __syncthreads();
#pragma unroll
    for (int mf = 0; mf < 6; ++mf) {
        const int cbase = wm * 96 + mf * 16;
        const int coct = (cbase >> 3) + (q >> 1);
#pragma unroll
        for (int nf = 0; nf < 2; ++nf) {
            const int ow = wn * 32 + nf * 16 + r;
            ushort pk[4];
#pragma unroll
            for (int rr = 0; rr < 4; ++rr) {
                const int oc = cbase + q * 4 + rr;
                float v = cacc[mf][nf][rr] * sc[oc] + bi[oc];
                v = (v >= 0.f) ? v : 0.1f * v;
                pk[rr] = f2b(v);
            }
            *reinterpret_cast<bf16x4*>(smem + (coct * 128 + ow) * 8 + (q & 1) * 4) =
                *reinterpret_cast<bf16x4*>(pk);
        }
    }
    __syncthreads();

    // ============ logits MFMA: wave-half mf split, shared af loads ============
    const int hi = wid >> 2;         // 0: mf 0..4, 1: mf 4..8
    const int mfbase = hi * 4;
    f32x4 macc[5], macc2[5];
#pragma unroll
    for (int mf = 0; mf < 5; ++mf) {
        macc[mf] = (f32x4){0.f, 0.f, 0.f, 0.f};
        macc2[mf] = (f32x4){0.f, 0.f, 0.f, 0.f};
    }
#pragma unroll
    for (int ks = 0; ks < 6; ++ks) {
        bf16x8 af[5];
        const ushort* ap = w2p + (((size_t)(ks * 9 + mfbase) * 64) + lane) * 8;
#pragma unroll
        for (int mf = 0; mf < 5; ++mf)
            af[mf] = *reinterpret_cast<const bf16x8*>(ap + (size_t)mf * 64 * 8);
        const bf16x8 bfr0 = *reinterpret_cast<const bf16x8*>(
            smem + ((ks * 4 + q) * 128 + (wid & 3) * 32 + r) * 8);
        const bf16x8 bfr1 = *reinterpret_cast<const bf16x8*>(
            smem + ((ks * 4 + q) * 128 + (wid & 3) * 32 + 16 + r) * 8);
#pragma unroll
        for (int mf = 0; mf < 5; ++mf) {
            macc[mf] = __builtin_amdgcn_mfma_f32_16x16x32_bf16(af[mf], bfr0, macc[mf], 0, 0, 0);
            macc2[mf] = __builtin_amdgcn_mfma_f32_16x16x32_bf16(af[mf], bfr1, macc2[mf], 0, 0, 0);
        }
    }
    __syncthreads();   // yl reads done; p overwrites

    // ===== branch-static softmax -> p[144][128] (rule #20: hi wave-uniform) =====
    if (hi == 0) {
#pragma unroll
        for (int nf = 0; nf < 2; ++nf) {
            const int ow = (wid & 3) * 32 + nf * 16 + r;
            const int col = (ow + q * 16) & 127;
            const f32x4(&mc)[5] = (nf == 0) ? macc : macc2;
#pragma unroll
            for (int gi = 0; gi < 2; ++gi) {
                const int gl = gi;                       // 0,1
                const int g = q * 4 + gl;
                float pv[9]; float mx = -1e30f;
#pragma unroll
                for (int k = 0; k < 9; ++k) {
                    const int s = gl * 9 + k;
                    pv[k] = mc[s >> 2][s & 3];
                    mx = fmaxf(mx, pv[k]);
                }
                float ssum = 0.f;
#pragma unroll
                for (int k = 0; k < 9; ++k) { pv[k] = __expf(pv[k] - mx); ssum += pv[k]; }
                const float inv = 1.f / ssum;
#pragma unroll
                for (int k = 0; k < 9; ++k)
                    smem[(g * 9 + k) * 128 + col] = f2b(pv[k] * inv);
            }
        }
    } else {
#pragma unroll
        for (int nf = 0; nf < 2; ++nf) {
            const int ow = (wid & 3) * 32 + nf * 16 + r;
            const int col = (ow + q * 16) & 127;
            const f32x4(&mc)[5] = (nf == 0) ? macc : macc2;
#pragma unroll
            for (int gi = 0; gi < 2; ++gi) {
                const int gl = 2 + gi;                   // 2,3
                const int g = q * 4 + gl;
                float pv[9]; float mx = -1e30f;
#pragma unroll
                for (int k = 0; k < 9; ++k) {
                    const int s = gl * 9 + k;
                    pv[k] = mc[(s >> 2) - 4][s & 3];
                    mx = fmaxf(mx, pv[k]);
                }
                float ssum = 0.f;
#pragma unroll
                for (int k = 0; k < 9; ++k) { pv[k] = __expf(pv[k] - mx); ssum += pv[k]; }
                const float inv = 1.f / ssum;
#pragma unroll
                for (int k = 0; k < 9; ++k)
                    smem[(g * 9 + k) * 128 + col] = f2b(pv[k] * inv);
            }
        }
    }
    __syncthreads();

    // ============ apply phase (coalesced) ============
    const int ih0 = 2 * oh - 1;
    const bool okh0 = (oh > 0);
#pragma unroll
    for (int it = 0; it < 4; ++it) {
        const int idx = (it << 9) + tid;
        const int g = idx >> 7;                 // 0..15, wave-uniform
        const int owl = idx & 127;
        const int owg = ow0 + owl;
        const int col = (owl + (g >> 2) * 16) & 127;

        float p[9];
#pragma unroll
        for (int k = 0; k < 9; ++k) p[k] = b2f(smem[(g * 9 + k) * 128 + col]);

        const int iw0 = 2 * owg - 1;
        const bool okw0 = (owg > 0);
#pragma unroll
        for (int i = 0; i < CPG; ++i) {
            const int cc = i * Gg + g;
            const float* xc = x + (size_t)(b * Cc + cc) * chs;
            float acc = 0.f;
#pragma unroll
            for (int kh = 0; kh < 3; ++kh) {
                if (kh == 0 && !okh0) continue;
                const float* rowp = xc + (size_t)(ih0 + kh) * Ww + iw0;
                const float v0 = okw0 ? rowp[0] : 0.f;
                const float2 v12 = *reinterpret_cast<const float2*>(rowp + 1);
                acc += p[kh * 3 + 0] * v0 + p[kh * 3 + 1] * v12.x
                     + p[kh * 3 + 2] * v12.y;
            }
            out[((size_t)(b * Cc + cc) * HO + oh) * WO + owg] = acc;
        }
    }
}

extern "C" void kernel_launch(void* const* d_in, const int* in_sizes, int n_in,
                              void* d_out, int out_size, void* d_ws, size_t ws_size,
                              hipStream_t stream) {
    const float* x     = (const float*)d_in[0];
    const float* w1    = (const float*)d_in[1];
    const float* gamma = (const float*)d_in[2];
    const float* beta  = (const float*)d_in[3];
    const float* w2    = (const float*)d_in[4];
    float* out = (float*)d_out;

    ushort* apack = (ushort*)d_ws;                           // 331,776 B
    ushort* w2p   = (ushort*)((char*)d_ws + 331776);         // + 55,296 B

    pack_w1<<<27 * 12, 64, 0, stream>>>(w1, apack);
    pack_w2<<<6 * 9, 64, 0, stream>>>(w2, w2p);
    fused<<<Bb * HO * 2, 512, 0, stream>>>(x, apack, w2p, gamma, beta, out);
}

// Round 17
// 175.049 us; speedup vs baseline: 2.0926x; 1.2900x over previous
//
#include <hip/hip_runtime.h>
#include <hip/hip_bf16.h>

#define Bb 4
#define Cc 96
#define Hh 256
#define Ww 512
#define OC 192
#define HO 128
#define WO 256
#define Gg 16
#define CPG 6

typedef __attribute__((ext_vector_type(4))) float f32x4;
typedef __attribute__((ext_vector_type(8))) short bf16x8;
typedef __attribute__((ext_vector_type(4))) short bf16x4;

static __device__ __forceinline__ ushort f2b(float f) {
    __hip_bfloat16 h = __float2bfloat16(f);
    return *reinterpret_cast<ushort*>(&h);
}
static __device__ __forceinline__ float b2f(ushort u) {
    unsigned int v = ((unsigned int)u) << 16;
    return __builtin_bit_cast(float, v);
}

// ---------------------------------------------------------------------------
// Pack w1, MFMA fragment order, klocal = q*8 + j (verified R7).
// ---------------------------------------------------------------------------
__global__ __launch_bounds__(64) void pack_w1(const float* __restrict__ w1,
                                              ushort* __restrict__ apack) {
    const int blk = blockIdx.x;      // 27*12
    const int k0 = blk / 12;
    const int mf = blk % 12;
    const int lane = threadIdx.x;
    const int m = mf * 16 + (lane & 15);
    const int chunk = k0 / 9;
    const int tap = k0 % 9;
    ushort* dst = apack + (((size_t)(k0 * 12 + mf) * 64) + lane) * 8;
#pragma unroll
    for (int j = 0; j < 8; ++j) {
        const int klocal = ((lane >> 4) << 3) + j;
        const int ic = chunk * 32 + klocal;
        dst[j] = f2b(w1[(size_t)(m * Cc + ic) * 9 + tap]);
    }
}

// ---------------------------------------------------------------------------
// Pack w2, softmax-group row permutation (verified R5) + klocal = q*8+j (R7).
// ---------------------------------------------------------------------------
__global__ __launch_bounds__(64) void pack_w2(const float* __restrict__ w2,
                                              ushort* __restrict__ w2p) {
    const int blk = blockIdx.x;      // 6*9
    const int ks = blk / 9;
    const int mf = blk % 9;
    const int lane = threadIdx.x;
    const int X = lane & 15;
    const int qq = X >> 2;
    const int rr = X & 3;
    const int s = mf * 4 + rr;
    const int g = qq * 4 + s / 9;
    const int k = s % 9;
    const int m = g * 9 + k;
    ushort* dst = w2p + (((size_t)(ks * 9 + mf) * 64) + lane) * 8;
#pragma unroll
    for (int j = 0; j < 8; ++j) {
        const int klocal = ((lane >> 4) << 3) + j;
        const int c = ks * 32 + klocal;
        dst[j] = f2b(w2[(size_t)m * OC + c]);
    }
}

// ---------------------------------------------------------------------------
// Fused kernel — R14 structure (measured optimum: 174.6 µs total).
// N-tile = 128, 512 threads (8 waves). Conv wave tile M=96 x N=32.
// Logits: wave-half mf split (wid<4: mf0..4, wid>=4: mf4..8; mf4 dup).
// LDS (octet-major): xl [6][4][128][8]=49152 B (+halo) | yl [24][128][8] |
// p [144][128] bf16 rotated. Grid 1024 (bijective XCD swizzle, 128/XCD).
// __launch_bounds__(512) only — 2nd arg proven neutral-or-harmful (R8/R10/R13).
// Register prefetch (T14) proven net-negative here (R15/R16): occupancy loss
// outweighs hidden staging latency. Keep implicit TLP.
// ---------------------------------------------------------------------------
#define XL_MAIN (6 * 4 * 128 * 8)         // 24576 ushorts
#define UNION_USHORTS (XL_MAIN + 3 * 32)  // 24672 ushorts = 49344 B

__global__ __launch_bounds__(512) void fused(
        const float* __restrict__ x, const ushort* __restrict__ apack,
        const ushort* __restrict__ w2p,
        const float* __restrict__ gamma, const float* __restrict__ beta,
        float* __restrict__ out) {
    __shared__ __align__(16) ushort smem[UNION_USHORTS];
    __shared__ float sc[OC], bi[OC];

    // bijective XCD swizzle (1024 % 8 == 0): 128 contiguous blocks per XCD
    const int bid0 = blockIdx.x;
    const int bid = (bid0 & 7) * 128 + (bid0 >> 3);
    const int owt = bid & 1;
    const int oh = (bid >> 1) & 127;
    const int b = bid >> 8;
    const int ow0 = owt * 128;
    const int tid = threadIdx.x;
    const int wid = tid >> 6;       // 0..7
    const int wm = wid & 1;         // conv M half: oc base wm*96
    const int wn = wid >> 1;        // conv N quarter: ow base wn*32
    const int lane = tid & 63;
    const int r = lane & 15;
    const int q = lane >> 4;

    if (tid < OC) {
        const float bnr = 1.0f / sqrtf(1.0f + 1e-5f);
        sc[tid] = gamma[tid] * bnr;
        bi[tid] = beta[tid];
    }

    f32x4 cacc[6][2];
#pragma unroll
    for (int mf = 0; mf < 6; ++mf)
#pragma unroll
        for (int nf = 0; nf < 2; ++nf) cacc[mf][nf] = (f32x4){0.f, 0.f, 0.f, 0.f};

    const size_t chs = (size_t)Hh * Ww;

    // ================= conv phase =================
    for (int chunk = 0; chunk < 3; ++chunk) {
        __syncthreads();
        const int icc = chunk * 32;
#pragma unroll
        for (int it = 0; it < 3; ++it) {
            const int g2 = tid + (it << 9);
            const int oct = g2 & 3;
            const int colp = (g2 >> 2) & 127;
            const int row = g2 >> 9;
            const int ih = 2 * oh - 1 + row;
            const int gcol = 2 * ow0 + 2 * colp;
            float2 v[8];
            if (ih >= 0) {
                const float* xp = x + ((size_t)(b * Cc + icc + (oct << 3)) * Hh + ih) * Ww + gcol;
#pragma unroll
                for (int j = 0; j < 8; ++j)
                    v[j] = *reinterpret_cast<const float2*>(xp + (size_t)j * chs);
            } else {
#pragma unroll
                for (int j = 0; j < 8; ++j) v[j] = make_float2(0.f, 0.f);
            }
            bf16x8 u0, u1;
#pragma unroll
            for (int j = 0; j < 8; ++j) {
                u0[j] = (short)f2b(v[j].x);
                u1[j] = (short)f2b(v[j].y);
            }
            *reinterpret_cast<bf16x8*>(smem + (((row * 2 + 0) * 4 + oct) * 128 + colp) * 8) = u0;
            *reinterpret_cast<bf16x8*>(smem + (((row * 2 + 1) * 4 + oct) * 128 + colp) * 8) = u1;
        }
        if (tid < 12) {
            const int oct = tid & 3;
            const int row = tid >> 2;
            const int ih = 2 * oh - 1 + row;
            const int gcol = 2 * ow0 - 1;
            float v[8];
            if (ih >= 0 && gcol >= 0) {
                const float* xp = x + ((size_t)(b * Cc + icc + (oct << 3)) * Hh + ih) * Ww + gcol;
#pragma unroll
                for (int j = 0; j < 8; ++j) v[j] = xp[(size_t)j * chs];
            } else {
#pragma unroll
                for (int j = 0; j < 8; ++j) v[j] = 0.f;
            }
            bf16x8 u;
#pragma unroll
            for (int j = 0; j < 8; ++j) u[j] = (short)f2b(v[j]);
            *reinterpret_cast<bf16x8*>(smem + XL_MAIN + row * 32 + oct * 8) = u;
        }
        __syncthreads();

#pragma unroll
        for (int tap = 0; tap < 9; ++tap) {
            const int kh = tap / 3, kw = tap % 3;
            const int par = (kw == 1) ? 0 : 1;
            const int cb = (kw == 0) ? -1 : 0;
            const int k0 = chunk * 9 + tap;

            bf16x8 af[6];
            const ushort* ap = apack + (((size_t)(k0 * 12 + wm * 6) * 64) + lane) * 8;
#pragma unroll
            for (int mf = 0; mf < 6; ++mf)
                af[mf] = *reinterpret_cast<const bf16x8*>(ap + (size_t)mf * 64 * 8);

            bf16x8 bfr[2];
#pragma unroll
            for (int nf = 0; nf < 2; ++nf) {
                const int n = wn * 32 + nf * 16 + r;
                const int colc = n + cb;
                const ushort* src = (colc >= 0)
                    ? smem + (((kh * 2 + par) * 4 + q) * 128 + colc) * 8
                    : smem + XL_MAIN + kh * 32 + q * 8;
                bfr[nf] = *reinterpret_cast<const bf16x8*>(src);
            }
#pragma unroll
            for (int mf = 0; mf < 6; ++mf)
#pragma unroll
                for (int nf = 0; nf < 2; ++nf)
                    cacc[mf][nf] = __builtin_amdgcn_mfma_f32_16x16x32_bf16(
                        af[mf], bfr[nf], cacc[mf][nf], 0, 0, 0);
        }
    }

    // ====== epilogue: BN+LReLU -> yl[coct][ow][8] bf16 ======
    __syncthreads();
#pragma unroll
    for (int mf = 0; mf < 6; ++mf) {
        const int cbase = wm * 96 + mf * 16;
        const int coct = (cbase >> 3) + (q >> 1);
#pragma unroll
        for (int nf = 0; nf < 2; ++nf) {
            const int ow = wn * 32 + nf * 16 + r;
            ushort pk[4];
#pragma unroll
            for (int rr = 0; rr < 4; ++rr) {
                const int oc = cbase + q * 4 + rr;
                float v = cacc[mf][nf][rr] * sc[oc] + bi[oc];
                v = (v >= 0.f) ? v : 0.1f * v;
                pk[rr] = f2b(v);
            }
            *reinterpret_cast<bf16x4*>(smem + (coct * 128 + ow) * 8 + (q & 1) * 4) =
                *reinterpret_cast<bf16x4*>(pk);
        }
    }
    __syncthreads();

    // ============ logits MFMA: wave-half mf split, shared af loads ============
    const int hi = wid >> 2;         // 0: mf 0..4, 1: mf 4..8
    const int mfbase = hi * 4;
    f32x4 macc[5], macc2[5];
#pragma unroll
    for (int mf = 0; mf < 5; ++mf) {
        macc[mf] = (f32x4){0.f, 0.f, 0.f, 0.f};
        macc2[mf] = (f32x4){0.f, 0.f, 0.f, 0.f};
    }
#pragma unroll
    for (int ks = 0; ks < 6; ++ks) {
        bf16x8 af[5];
        const ushort* ap = w2p + (((size_t)(ks * 9 + mfbase) * 64) + lane) * 8;
#pragma unroll
        for (int mf = 0; mf < 5; ++mf)
            af[mf] = *reinterpret_cast<const bf16x8*>(ap + (size_t)mf * 64 * 8);
        const bf16x8 bfr0 = *reinterpret_cast<const bf16x8*>(
            smem + ((ks * 4 + q) * 128 + (wid & 3) * 32 + r) * 8);
        const bf16x8 bfr1 = *reinterpret_cast<const bf16x8*>(
            smem + ((ks * 4 + q) * 128 + (wid & 3) * 32 + 16 + r) * 8);
#pragma unroll
        for (int mf = 0; mf < 5; ++mf) {
            macc[mf] = __builtin_amdgcn_mfma_f32_16x16x32_bf16(af[mf], bfr0, macc[mf], 0, 0, 0);
            macc2[mf] = __builtin_amdgcn_mfma_f32_16x16x32_bf16(af[mf], bfr1, macc2[mf], 0, 0, 0);
        }
    }
    __syncthreads();   // yl reads done; p overwrites

    // ===== branch-static softmax -> p[144][128] (rule #20: hi wave-uniform) =====
    if (hi == 0) {
#pragma unroll
        for (int nf = 0; nf < 2; ++nf) {
            const int ow = (wid & 3) * 32 + nf * 16 + r;
            const int col = (ow + q * 16) & 127;
            const f32x4(&mc)[5] = (nf == 0) ? macc : macc2;
#pragma unroll
            for (int gi = 0; gi < 2; ++gi) {
                const int gl = gi;                       // 0,1
                const int g = q * 4 + gl;
                float pv[9]; float mx = -1e30f;
#pragma unroll
                for (int k = 0; k < 9; ++k) {
                    const int s = gl * 9 + k;
                    pv[k] = mc[s >> 2][s & 3];
                    mx = fmaxf(mx, pv[k]);
                }
                float ssum = 0.f;
#pragma unroll
                for (int k = 0; k < 9; ++k) { pv[k] = __expf(pv[k] - mx); ssum += pv[k]; }
                const float inv = 1.f / ssum;
#pragma unroll
                for (int k = 0; k < 9; ++k)
                    smem[(g * 9 + k) * 128 + col] = f2b(pv[k] * inv);
            }
        }
    } else {
#pragma unroll
        for (int nf = 0; nf < 2; ++nf) {
            const int ow = (wid & 3) * 32 + nf * 16 + r;
            const int col = (ow + q * 16) & 127;
            const f32x4(&mc)[5] = (nf == 0) ? macc : macc2;
#pragma unroll
            for (int gi = 0; gi < 2; ++gi) {
                const int gl = 2 + gi;                   // 2,3
                const int g = q * 4 + gl;
                float pv[9]; float mx = -1e30f;
#pragma unroll
                for (int k = 0; k < 9; ++k) {
                    const int s = gl * 9 + k;
                    pv[k] = mc[(s >> 2) - 4][s & 3];
                    mx = fmaxf(mx, pv[k]);
                }
                float ssum = 0.f;
#pragma unroll
                for (int k = 0; k < 9; ++k) { pv[k] = __expf(pv[k] - mx); ssum += pv[k]; }
                const float inv = 1.f / ssum;
#pragma unroll
                for (int k = 0; k < 9; ++k)
                    smem[(g * 9 + k) * 128 + col] = f2b(pv[k] * inv);
            }
        }
    }
    __syncthreads();

    // ============ apply phase (coalesced) ============
    const int ih0 = 2 * oh - 1;
    const bool okh0 = (oh > 0);
#pragma unroll
    for (int it = 0; it < 4; ++it) {
        const int idx = (it << 9) + tid;
        const int g = idx >> 7;                 // 0..15, wave-uniform
        const int owl = idx & 127;
        const int owg = ow0 + owl;
        const int col = (owl + (g >> 2) * 16) & 127;

        float p[9];
#pragma unroll
        for (int k = 0; k < 9; ++k) p[k] = b2f(smem[(g * 9 + k) * 128 + col]);

        const int iw0 = 2 * owg - 1;
        const bool okw0 = (owg > 0);
#pragma unroll
        for (int i = 0; i < CPG; ++i) {
            const int cc = i * Gg + g;
            const float* xc = x + (size_t)(b * Cc + cc) * chs;
            float acc = 0.f;
#pragma unroll
            for (int kh = 0; kh < 3; ++kh) {
                if (kh == 0 && !okh0) continue;
                const float* rowp = xc + (size_t)(ih0 + kh) * Ww + iw0;
                const float v0 = okw0 ? rowp[0] : 0.f;
                const float2 v12 = *reinterpret_cast<const float2*>(rowp + 1);
                acc += p[kh * 3 + 0] * v0 + p[kh * 3 + 1] * v12.x
                     + p[kh * 3 + 2] * v12.y;
            }
            out[((size_t)(b * Cc + cc) * HO + oh) * WO + owg] = acc;
        }
    }
}

extern "C" void kernel_launch(void* const* d_in, const int* in_sizes, int n_in,
                              void* d_out, int out_size, void* d_ws, size_t ws_size,
                              hipStream_t stream) {
    const float* x     = (const float*)d_in[0];
    const float* w1    = (const float*)d_in[1];
    const float* gamma = (const float*)d_in[2];
    const float* beta  = (const float*)d_in[3];
    const float* w2    = (const float*)d_in[4];
    float* out = (float*)d_out;

    ushort* apack = (ushort*)d_ws;                           // 331,776 B
    ushort* w2p   = (ushort*)((char*)d_ws + 331776);         // + 55,296 B

    pack_w1<<<27 * 12, 64, 0, stream>>>(w1, apack);
    pack_w2<<<6 * 9, 64, 0, stream>>>(w2, w2p);
    fused<<<Bb * HO * 2, 512, 0, stream>>>(x, apack, w2p, gamma, beta, out);
}